// Round 4
// baseline (763.682 us; speedup 1.0000x reference)
//
#include <hip/hip_runtime.h>

typedef float f32x4 __attribute__((ext_vector_type(4)));
typedef short s16x8 __attribute__((ext_vector_type(8)));
typedef unsigned short u16x4 __attribute__((ext_vector_type(4)));
typedef unsigned short ushort_t;

__device__ __forceinline__ unsigned short f2bf(float f) {
    union { float f; unsigned int u; } v; v.f = f;
    unsigned int r = (v.u + 0x7fffu + ((v.u >> 16) & 1u)) >> 16;
    return (unsigned short)r;
}
__device__ __forceinline__ float bf2f(unsigned short b) {
    union { unsigned int u; float f; } v; v.u = ((unsigned int)b) << 16;
    return v.f;
}

__device__ __forceinline__ f32x4 mfma_bf16(s16x8 a, s16x8 b, f32x4 c) {
    return __builtin_amdgcn_mfma_f32_16x16x32_bf16(a, b, c, 0, 0, 0);
}

__device__ __forceinline__ void gl_lds16(const void* g, void* l) {
    __builtin_amdgcn_global_load_lds(
        (const __attribute__((address_space(1))) unsigned int*)g,
        (__attribute__((address_space(3))) unsigned int*)l, 16, 0, 0);
}

// log2(e)/sqrt(512): fold exp->exp2 conversion into Q scale
#define QSCALE 0.06375871469f
#define DEFER_THR 11.5416f   // 8 nats in log2 units

// ---------------------------------------------------------------------------
// Kernel 1: QKV projection. y = relu(x @ W^T + b); q *= log2(e)/sqrt(512).
// q,k row-major [batch*4096][512]; v TRANSPOSED [batch][512][4096].
// ---------------------------------------------------------------------------
#define PLDK 40

__global__ __launch_bounds__(256) void qkv_proj(
    const float* __restrict__ x,
    const float* __restrict__ Wq, const float* __restrict__ bq,
    const float* __restrict__ Wk, const float* __restrict__ bk,
    const float* __restrict__ Wv, const float* __restrict__ bv,
    ushort_t* __restrict__ qkv_ws)
{
    const int mblk  = blockIdx.x;
    const int nblk  = blockIdx.y;
    const int which = blockIdx.z;

    const float* W    = (which == 0) ? Wq : (which == 1) ? Wk : Wv;
    const float* bias = (which == 0) ? bq : (which == 1) ? bk : bv;
    ushort_t* out = qkv_ws + (size_t)which * (8192u * 512u);
    const float scale = (which == 0) ? QSCALE : 1.0f;

    __shared__ ushort_t a_lds[128][PLDK];
    __shared__ ushort_t b_lds[128][PLDK];

    const int tid  = threadIdx.x;
    const int lane = tid & 63;
    const int wave = tid >> 6;
    const int wr = wave >> 1, wc = wave & 1;

    const int srow = tid >> 1;
    const int scol = (tid & 1) * 16;

    f32x4 acc[4][4] = {};

    for (int k0 = 0; k0 < 512; k0 += 32) {
        {
            const float* src = x + (size_t)(mblk * 128 + srow) * 512 + k0 + scol;
            ushort_t tmp[16];
            #pragma unroll
            for (int i = 0; i < 16; i++) tmp[i] = f2bf(src[i]);
            #pragma unroll
            for (int i = 0; i < 16; i++) a_lds[srow][scol + i] = tmp[i];
        }
        {
            const float* src = W + (size_t)(nblk * 128 + srow) * 512 + k0 + scol;
            ushort_t tmp[16];
            #pragma unroll
            for (int i = 0; i < 16; i++) tmp[i] = f2bf(src[i]);
            #pragma unroll
            for (int i = 0; i < 16; i++) b_lds[srow][scol + i] = tmp[i];
        }
        __syncthreads();

        s16x8 af[4], bf[4];
        #pragma unroll
        for (int m = 0; m < 4; m++)
            af[m] = *reinterpret_cast<const s16x8*>(&a_lds[wr * 64 + m * 16 + (lane & 15)][(lane >> 4) * 8]);
        #pragma unroll
        for (int n = 0; n < 4; n++)
            bf[n] = *reinterpret_cast<const s16x8*>(&b_lds[wc * 64 + n * 16 + (lane & 15)][(lane >> 4) * 8]);

        #pragma unroll
        for (int m = 0; m < 4; m++)
            #pragma unroll
            for (int n = 0; n < 4; n++)
                acc[m][n] = mfma_bf16(af[m], bf[n], acc[m][n]);

        __syncthreads();
    }

    if (which == 2) {
        #pragma unroll
        for (int n = 0; n < 4; n++) {
            const int col = nblk * 128 + wc * 64 + n * 16 + (lane & 15);
            const float b = bias[col];
            #pragma unroll
            for (int m = 0; m < 4; m++) {
                const int rowb = mblk * 128 + wr * 64 + m * 16 + (lane >> 4) * 4;
                const int batch = rowb >> 12, sr = rowb & 4095;
                u16x4 pk;
                #pragma unroll
                for (int j = 0; j < 4; j++)
                    pk[j] = f2bf(fmaxf(acc[m][n][j] + b, 0.0f));
                *reinterpret_cast<u16x4*>(out + (size_t)batch * 512 * 4096 +
                                          (size_t)col * 4096 + sr) = pk;
            }
        }
    } else {
        #pragma unroll
        for (int n = 0; n < 4; n++) {
            const int col = nblk * 128 + wc * 64 + n * 16 + (lane & 15);
            const float b = bias[col];
            #pragma unroll
            for (int m = 0; m < 4; m++) {
                #pragma unroll
                for (int j = 0; j < 4; j++) {
                    const int row = mblk * 128 + wr * 64 + m * 16 + (lane >> 4) * 4 + j;
                    float v = fmaxf(acc[m][n][j] + b, 0.0f) * scale;
                    out[(size_t)row * 512 + col] = f2bf(v);
                }
            }
        }
    }
}

// ---------------------------------------------------------------------------
// Kernel 2: flash attention. 4 waves x 32 q-rows (2 MFMA row-frags each) =
// 128 rows/block, 256 threads. Each kf/vf LDS read feeds 2 MFMAs (halved
// LDS traffic vs 16-row waves). 2-phase double-buffered KV staging.
// grid = (2*SP, 32) = 256 blocks at SP=4 -> 1 block/CU.
// ---------------------------------------------------------------------------
__global__ __launch_bounds__(256, 1) void attn_v4(
    const ushort_t* __restrict__ qkv_ws,
    ushort_t* __restrict__ opart, float* __restrict__ ml,
    float* __restrict__ out, int SP, int NK)
{
    const int combo = blockIdx.x;
    const int batch = combo / SP;
    const int split = combo % SP;
    const int qblk  = blockIdx.y;
    const int tid = threadIdx.x, lane = tid & 63, wave = tid >> 6;
    const int kv00 = split * (4096 / SP);

    const ushort_t* q_ws  = qkv_ws;
    const ushort_t* k_ws  = qkv_ws + (size_t)8192 * 512;
    const ushort_t* vt_ws = qkv_ws + (size_t)2 * 8192 * 512;  // [batch][512][4096]
    const size_t base  = (size_t)batch * 4096 * 512;
    const size_t vbase = (size_t)batch * 512 * 4096;

    __shared__ ushort_t k_lds[2][32 * 512];    // 2 x 32KB, swizzled
    __shared__ ushort_t vt_lds[2][512 * 32];   // 2 x 32KB, swizzled
    __shared__ ushort_t p_lds[4][32][40];      // per-wave P bounce (32 rows)

    const int g = lane >> 4;

    // resident Q fragments: 2 row-frags x 16 k-steps (128 VGPR)
    s16x8 qf0[16], qf1[16];
    {
        const int qrow0 = qblk * 128 + wave * 32 + (lane & 15);
        const ushort_t* qp0 = q_ws + base + (size_t)qrow0 * 512 + g * 8;
        const ushort_t* qp1 = qp0 + 16 * 512;
        #pragma unroll
        for (int ks = 0; ks < 16; ks++) {
            qf0[ks] = *reinterpret_cast<const s16x8*>(qp0 + ks * 32);
            qf1[ks] = *reinterpret_cast<const s16x8*>(qp1 + ks * 32);
        }
    }

    const f32x4 zf = {0.f, 0.f, 0.f, 0.f};
    f32x4 o0[32], o1[32];
    #pragma unroll
    for (int n = 0; n < 32; n++) { o0[n] = zf; o1[n] = zf; }
    float mrow[2][4], lrow[2][4];
    #pragma unroll
    for (int f = 0; f < 2; f++)
        #pragma unroll
        for (int j = 0; j < 4; j++) { mrow[f][j] = -1e30f; lrow[f][j] = 0.0f; }

#define STAGE(BUF, KV0)                                                         \
    do {                                                                        \
        _Pragma("unroll")                                                       \
        for (int i = 0; i < 8; i++) {                                           \
            const int C   = i * 4096 + tid * 16;                                \
            const int row = C >> 10;                                            \
            const int Lc  = (C & 1023) ^ ((row & 7) << 4);                      \
            gl_lds16(k_ws + base + (size_t)((KV0) + row) * 512 + (Lc >> 1),     \
                     (char*)&k_lds[BUF][0] + C);                                \
        }                                                                       \
        _Pragma("unroll")                                                       \
        for (int i = 0; i < 8; i++) {                                           \
            const int C    = i * 4096 + tid * 16;                               \
            const int drow = C >> 6;                                            \
            const int gc   = (C >> 4) & 3;                                      \
            const int gl   = gc ^ ((drow >> 1) & 3);                            \
            gl_lds16(vt_ws + vbase + (size_t)drow * 4096 + (KV0) + gl * 8,      \
                     (char*)&vt_lds[BUF][0] + C);                               \
        }                                                                       \
    } while (0)

    // prologue
    STAGE(0, kv00);
    asm volatile("s_waitcnt vmcnt(0)" ::: "memory");
    __builtin_amdgcn_s_barrier();

    int cur = 0;
    for (int it = 0; it < NK; ++it) {
        if (it + 1 < NK) STAGE(cur ^ 1, kv00 + (it + 1) * 32);

        const char* kb = (const char*)&k_lds[cur][0];
        const char* vb = (const char*)&vt_lds[cur][0];

        // ---- QK^T : S[32 rows][32 keys]; each kf read feeds 2 MFMAs
        f32x4 s00 = zf, s01 = zf, s10 = zf, s11 = zf;
        #pragma unroll
        for (int ks = 0; ks < 16; ++ks) {
            const int key0 = lane & 15;
            const s16x8 kf0 = *reinterpret_cast<const s16x8*>(
                kb + key0 * 1024 + ((ks * 64 + g * 16) ^ ((key0 & 7) << 4)));
            s00 = mfma_bf16(qf0[ks], kf0, s00);
            s10 = mfma_bf16(qf1[ks], kf0, s10);
            const int key1 = 16 + (lane & 15);
            const s16x8 kf1 = *reinterpret_cast<const s16x8*>(
                kb + key1 * 1024 + ((ks * 64 + g * 16) ^ ((key1 & 7) << 4)));
            s01 = mfma_bf16(qf0[ks], kf1, s01);
            s11 = mfma_bf16(qf1[ks], kf1, s11);
        }

        // ---- tile max per row (16-lane group reduce)
        float pmax[2][4];
        #pragma unroll
        for (int j = 0; j < 4; j++) {
            float mt0 = fmaxf(s00[j], s01[j]);
            float mt1 = fmaxf(s10[j], s11[j]);
            #pragma unroll
            for (int msk = 8; msk >= 1; msk >>= 1) {
                mt0 = fmaxf(mt0, __shfl_xor(mt0, msk, 64));
                mt1 = fmaxf(mt1, __shfl_xor(mt1, msk, 64));
            }
            pmax[0][j] = mt0; pmax[1][j] = mt1;
        }

        // ---- deferred rescale (T13)
        int need = 0;
        #pragma unroll
        for (int f = 0; f < 2; f++)
            #pragma unroll
            for (int j = 0; j < 4; j++)
                need |= (pmax[f][j] > mrow[f][j] + DEFER_THR) ? 1 : 0;
        if (__any(need)) {
            #pragma unroll
            for (int j = 0; j < 4; j++) {
                const float mn0 = fmaxf(mrow[0][j], pmax[0][j]);
                const float fc0 = exp2f(mrow[0][j] - mn0);
                mrow[0][j] = mn0; lrow[0][j] *= fc0;
                const float mn1 = fmaxf(mrow[1][j], pmax[1][j]);
                const float fc1 = exp2f(mrow[1][j] - mn1);
                mrow[1][j] = mn1; lrow[1][j] *= fc1;
                #pragma unroll
                for (int n = 0; n < 32; n++) { o0[n][j] *= fc0; o1[n][j] *= fc1; }
            }
        }

        // ---- P = exp2(S - m), row-sum, stash to per-wave LDS bounce
        #pragma unroll
        for (int j = 0; j < 4; j++) {
            const float p00 = exp2f(s00[j] - mrow[0][j]);
            const float p01 = exp2f(s01[j] - mrow[0][j]);
            const float p10 = exp2f(s10[j] - mrow[1][j]);
            const float p11 = exp2f(s11[j] - mrow[1][j]);
            float rs0 = p00 + p01, rs1 = p10 + p11;
            #pragma unroll
            for (int msk = 8; msk >= 1; msk >>= 1) {
                rs0 += __shfl_xor(rs0, msk, 64);
                rs1 += __shfl_xor(rs1, msk, 64);
            }
            lrow[0][j] += rs0; lrow[1][j] += rs1;
            const int pr = g * 4 + j;
            p_lds[wave][pr][lane & 15]       = f2bf(p00);
            p_lds[wave][pr][16 + (lane & 15)] = f2bf(p01);
            p_lds[wave][16 + pr][lane & 15]       = f2bf(p10);
            p_lds[wave][16 + pr][16 + (lane & 15)] = f2bf(p11);
        }

        const s16x8 pf0 = *reinterpret_cast<const s16x8*>(
            &p_lds[wave][lane & 15][g * 8]);
        const s16x8 pf1 = *reinterpret_cast<const s16x8*>(
            &p_lds[wave][16 + (lane & 15)][g * 8]);

        // ---- PV: each vf read feeds 2 MFMAs
        #pragma unroll
        for (int n = 0; n < 32; n++) {
            const int d = n * 16 + (lane & 15);
            const s16x8 vf = *reinterpret_cast<const s16x8*>(
                vb + d * 64 + ((g * 16) ^ (((d >> 1) & 3) << 4)));
            o0[n] = mfma_bf16(pf0, vf, o0[n]);
            o1[n] = mfma_bf16(pf1, vf, o1[n]);
        }

        asm volatile("s_waitcnt vmcnt(0)" ::: "memory");
        __builtin_amdgcn_s_barrier();
        cur ^= 1;
    }
#undef STAGE

    // ---- epilogue
    const int qrowb = qblk * 128 + wave * 32;
    if (opart != nullptr) {
        const size_t prow8k = (size_t)batch * 4096;
        if ((lane & 15) == 0) {
            #pragma unroll
            for (int j = 0; j < 4; j++) {
                const size_t r0 = prow8k + qrowb + g * 4 + j;
                ml[((size_t)split * 8192 + r0) * 2]     = mrow[0][j];
                ml[((size_t)split * 8192 + r0) * 2 + 1] = lrow[0][j];
                const size_t r1 = r0 + 16;
                ml[((size_t)split * 8192 + r1) * 2]     = mrow[1][j];
                ml[((size_t)split * 8192 + r1) * 2 + 1] = lrow[1][j];
            }
        }
        ushort_t* op = opart + (size_t)split * 8192 * 512;
        #pragma unroll
        for (int n = 0; n < 32; n++) {
            #pragma unroll
            for (int j = 0; j < 4; j++) {
                const size_t r0 = prow8k + qrowb + g * 4 + j;
                op[r0 * 512 + n * 16 + (lane & 15)] = f2bf(o0[n][j]);
                op[(r0 + 16) * 512 + n * 16 + (lane & 15)] = f2bf(o1[n][j]);
            }
        }
    } else {
        float inv0[4], inv1[4];
        #pragma unroll
        for (int j = 0; j < 4; j++) {
            inv0[j] = 1.0f / lrow[0][j];
            inv1[j] = 1.0f / lrow[1][j];
        }
        #pragma unroll
        for (int n = 0; n < 32; n++) {
            #pragma unroll
            for (int j = 0; j < 4; j++) {
                const int row = qrowb + g * 4 + j;
                out[base + (size_t)row * 512 + n * 16 + (lane & 15)] = o0[n][j] * inv0[j];
                out[base + (size_t)(row + 16) * 512 + n * 16 + (lane & 15)] = o1[n][j] * inv1[j];
            }
        }
    }
}

// ---------------------------------------------------------------------------
// Kernel 3: merge KV-split partials (exp2 domain). 1 wave/row, 4 rows/block.
// ---------------------------------------------------------------------------
__global__ __launch_bounds__(256) void merge_kernel(
    const ushort_t* __restrict__ opart, const float* __restrict__ ml,
    float* __restrict__ out, int SP)
{
    const int row  = blockIdx.x * 4 + (threadIdx.x >> 6);
    const int lane = threadIdx.x & 63;

    float M = -1e30f;
    for (int s = 0; s < SP; s++)
        M = fmaxf(M, ml[((size_t)s * 8192 + row) * 2]);
    float denom = 0.0f, w[4];
    for (int s = 0; s < SP; s++) {
        w[s] = exp2f(ml[((size_t)s * 8192 + row) * 2] - M);
        denom += w[s] * ml[((size_t)s * 8192 + row) * 2 + 1];
    }
    const float inv = 1.0f / denom;

    float acc[8] = {};
    for (int s = 0; s < SP; s++) {
        const s16x8 v = *reinterpret_cast<const s16x8*>(
            opart + ((size_t)s * 8192 + row) * 512 + lane * 8);
        #pragma unroll
        for (int i = 0; i < 8; i++)
            acc[i] += w[s] * bf2f((ushort_t)v[i]);
    }
    float* dst = out + (size_t)row * 512 + lane * 8;
    #pragma unroll
    for (int i = 0; i < 8; i++) dst[i] = acc[i] * inv;
}

extern "C" void kernel_launch(void* const* d_in, const int* in_sizes, int n_in,
                              void* d_out, int out_size, void* d_ws, size_t ws_size,
                              hipStream_t stream) {
    const float* x  = (const float*)d_in[0];
    const float* Wq = (const float*)d_in[1];
    const float* bq = (const float*)d_in[2];
    const float* Wk = (const float*)d_in[3];
    const float* bk = (const float*)d_in[4];
    const float* Wv = (const float*)d_in[5];
    const float* bv = (const float*)d_in[6];
    float* out = (float*)d_out;
    ushort_t* qkv = (ushort_t*)d_ws;  // q | k | vt, each 8192*512 bf16
    (void)in_sizes; (void)n_in; (void)out_size;

    const size_t qkv_bytes = 3ull * 8192 * 512 * 2;  // 25165824

    int SP = 0;
    if (ws_size >= qkv_bytes + 4ull * (8388608 + 65536)) SP = 4;
    else if (ws_size >= qkv_bytes + 2ull * (8388608 + 65536)) SP = 2;
    else if (ws_size >= qkv_bytes + 1ull * (8388608 + 65536)) SP = 1;

    dim3 gp(64, 4, 3);
    qkv_proj<<<gp, 256, 0, stream>>>(x, Wq, bq, Wk, bk, Wv, bv, qkv);

    if (SP > 0) {
        ushort_t* opart = qkv + 3ull * 8192 * 512;
        float* ml = (float*)(opart + (size_t)SP * 8192 * 512);
        dim3 ga(2 * SP, 32);
        attn_v4<<<ga, 256, 0, stream>>>(qkv, opart, ml, out, SP, (4096 / SP) / 32);
        merge_kernel<<<2048, 256, 0, stream>>>(opart, ml, out, SP);
    } else {
        dim3 ga(2, 32);
        attn_v4<<<ga, 256, 0, stream>>>(qkv, nullptr, nullptr, out, 1, 128);
    }
}

// Round 5
// 197.004 us; speedup vs baseline: 3.8765x; 3.8765x over previous
//
#include <hip/hip_runtime.h>

typedef float f32x4 __attribute__((ext_vector_type(4)));
typedef short s16x8 __attribute__((ext_vector_type(8)));
typedef unsigned short u16x4 __attribute__((ext_vector_type(4)));
typedef unsigned short ushort_t;

__device__ __forceinline__ unsigned short f2bf(float f) {
    union { float f; unsigned int u; } v; v.f = f;
    unsigned int r = (v.u + 0x7fffu + ((v.u >> 16) & 1u)) >> 16;
    return (unsigned short)r;
}
__device__ __forceinline__ float bf2f(unsigned short b) {
    union { unsigned int u; float f; } v; v.u = ((unsigned int)b) << 16;
    return v.f;
}

__device__ __forceinline__ f32x4 mfma_bf16(s16x8 a, s16x8 b, f32x4 c) {
    return __builtin_amdgcn_mfma_f32_16x16x32_bf16(a, b, c, 0, 0, 0);
}

__device__ __forceinline__ void gl_lds16(const void* g, void* l) {
    __builtin_amdgcn_global_load_lds(
        (const __attribute__((address_space(1))) unsigned int*)g,
        (__attribute__((address_space(3))) unsigned int*)l, 16, 0, 0);
}

// log2(e)/sqrt(512): fold exp->exp2 conversion into Q scale
#define QSCALE 0.06375871469f
// Fixed softmax offset (log2 domain). Valid because relu(q)·relu(k) >= 0 and
// |s'| <= |q||k|*log2e/sqrt(512) <~ 16. Softmax is shift-invariant, so this is
// mathematically exact; numerically p in [2^-18, 2^(s'max-18)], no overflow,
// denominator >= 4096*2^-18 > 0. Eliminates online max/rescale entirely.
#define FIXED_M 18.0f

// ---------------------------------------------------------------------------
// Kernel 1: QKV projection. y = relu(x @ W^T + b); q *= log2(e)/sqrt(512).
// q,k row-major [batch*4096][512]; v TRANSPOSED [batch][512][4096].
// ---------------------------------------------------------------------------
#define PLDK 40

__global__ __launch_bounds__(256) void qkv_proj(
    const float* __restrict__ x,
    const float* __restrict__ Wq, const float* __restrict__ bq,
    const float* __restrict__ Wk, const float* __restrict__ bk,
    const float* __restrict__ Wv, const float* __restrict__ bv,
    ushort_t* __restrict__ qkv_ws)
{
    const int mblk  = blockIdx.x;
    const int nblk  = blockIdx.y;
    const int which = blockIdx.z;

    const float* W    = (which == 0) ? Wq : (which == 1) ? Wk : Wv;
    const float* bias = (which == 0) ? bq : (which == 1) ? bk : bv;
    ushort_t* out = qkv_ws + (size_t)which * (8192u * 512u);
    const float scale = (which == 0) ? QSCALE : 1.0f;

    __shared__ ushort_t a_lds[128][PLDK];
    __shared__ ushort_t b_lds[128][PLDK];

    const int tid  = threadIdx.x;
    const int lane = tid & 63;
    const int wave = tid >> 6;
    const int wr = wave >> 1, wc = wave & 1;

    const int srow = tid >> 1;
    const int scol = (tid & 1) * 16;

    f32x4 acc[4][4] = {};

    for (int k0 = 0; k0 < 512; k0 += 32) {
        {
            const float* src = x + (size_t)(mblk * 128 + srow) * 512 + k0 + scol;
            ushort_t tmp[16];
            #pragma unroll
            for (int i = 0; i < 16; i++) tmp[i] = f2bf(src[i]);
            #pragma unroll
            for (int i = 0; i < 16; i++) a_lds[srow][scol + i] = tmp[i];
        }
        {
            const float* src = W + (size_t)(nblk * 128 + srow) * 512 + k0 + scol;
            ushort_t tmp[16];
            #pragma unroll
            for (int i = 0; i < 16; i++) tmp[i] = f2bf(src[i]);
            #pragma unroll
            for (int i = 0; i < 16; i++) b_lds[srow][scol + i] = tmp[i];
        }
        __syncthreads();

        s16x8 af[4], bf[4];
        #pragma unroll
        for (int m = 0; m < 4; m++)
            af[m] = *reinterpret_cast<const s16x8*>(&a_lds[wr * 64 + m * 16 + (lane & 15)][(lane >> 4) * 8]);
        #pragma unroll
        for (int n = 0; n < 4; n++)
            bf[n] = *reinterpret_cast<const s16x8*>(&b_lds[wc * 64 + n * 16 + (lane & 15)][(lane >> 4) * 8]);

        #pragma unroll
        for (int m = 0; m < 4; m++)
            #pragma unroll
            for (int n = 0; n < 4; n++)
                acc[m][n] = mfma_bf16(af[m], bf[n], acc[m][n]);

        __syncthreads();
    }

    if (which == 2) {
        #pragma unroll
        for (int n = 0; n < 4; n++) {
            const int col = nblk * 128 + wc * 64 + n * 16 + (lane & 15);
            const float b = bias[col];
            #pragma unroll
            for (int m = 0; m < 4; m++) {
                const int rowb = mblk * 128 + wr * 64 + m * 16 + (lane >> 4) * 4;
                const int batch = rowb >> 12, sr = rowb & 4095;
                u16x4 pk;
                #pragma unroll
                for (int j = 0; j < 4; j++)
                    pk[j] = f2bf(fmaxf(acc[m][n][j] + b, 0.0f));
                *reinterpret_cast<u16x4*>(out + (size_t)batch * 512 * 4096 +
                                          (size_t)col * 4096 + sr) = pk;
            }
        }
    } else {
        #pragma unroll
        for (int n = 0; n < 4; n++) {
            const int col = nblk * 128 + wc * 64 + n * 16 + (lane & 15);
            const float b = bias[col];
            #pragma unroll
            for (int m = 0; m < 4; m++) {
                #pragma unroll
                for (int j = 0; j < 4; j++) {
                    const int row = mblk * 128 + wr * 64 + m * 16 + (lane >> 4) * 4 + j;
                    float v = fmaxf(acc[m][n][j] + b, 0.0f) * scale;
                    out[(size_t)row * 512 + col] = f2bf(v);
                }
            }
        }
    }
}

// ---------------------------------------------------------------------------
// Kernel 2: flash attention, fixed-offset softmax (no online max/rescale so
// O accumulators are pure MFMA state -> AGPRs). 4 waves x 32 q-rows = 128
// rows/block, 256 threads. 2-phase double-buffered KV staging.
// grid = (2*SP, 32) = 256 blocks at SP=4 -> 1 block/CU.
// ---------------------------------------------------------------------------
__global__ __launch_bounds__(256, 1) void attn_v5(
    const ushort_t* __restrict__ qkv_ws,
    ushort_t* __restrict__ opart, float* __restrict__ ml,
    float* __restrict__ out, int SP, int NK)
{
    const int combo = blockIdx.x;
    const int batch = combo / SP;
    const int split = combo % SP;
    const int qblk  = blockIdx.y;
    const int tid = threadIdx.x, lane = tid & 63, wave = tid >> 6;
    const int kv00 = split * (4096 / SP);

    const ushort_t* q_ws  = qkv_ws;
    const ushort_t* k_ws  = qkv_ws + (size_t)8192 * 512;
    const ushort_t* vt_ws = qkv_ws + (size_t)2 * 8192 * 512;  // [batch][512][4096]
    const size_t base  = (size_t)batch * 4096 * 512;
    const size_t vbase = (size_t)batch * 512 * 4096;

    __shared__ ushort_t k_lds[2][32 * 512];    // 2 x 32KB, swizzled
    __shared__ ushort_t vt_lds[2][512 * 32];   // 2 x 32KB, swizzled
    __shared__ ushort_t p_lds[4][32][40];      // per-wave P bounce (32 rows)

    const int g = lane >> 4;

    // resident Q fragments: 2 row-frags x 16 k-steps (128 VGPR)
    s16x8 qf0[16], qf1[16];
    {
        const int qrow0 = qblk * 128 + wave * 32 + (lane & 15);
        const ushort_t* qp0 = q_ws + base + (size_t)qrow0 * 512 + g * 8;
        const ushort_t* qp1 = qp0 + 16 * 512;
        #pragma unroll
        for (int ks = 0; ks < 16; ks++) {
            qf0[ks] = *reinterpret_cast<const s16x8*>(qp0 + ks * 32);
            qf1[ks] = *reinterpret_cast<const s16x8*>(qp1 + ks * 32);
        }
    }

    const f32x4 zf = {0.f, 0.f, 0.f, 0.f};
    f32x4 o0[32], o1[32];
    #pragma unroll
    for (int n = 0; n < 32; n++) { o0[n] = zf; o1[n] = zf; }
    float lrow[2][4];
    #pragma unroll
    for (int f = 0; f < 2; f++)
        #pragma unroll
        for (int j = 0; j < 4; j++) lrow[f][j] = 0.0f;

#define STAGE(BUF, KV0)                                                         \
    do {                                                                        \
        _Pragma("unroll")                                                       \
        for (int i = 0; i < 8; i++) {                                           \
            const int C   = i * 4096 + tid * 16;                                \
            const int row = C >> 10;                                            \
            const int Lc  = (C & 1023) ^ ((row & 7) << 4);                      \
            gl_lds16(k_ws + base + (size_t)((KV0) + row) * 512 + (Lc >> 1),     \
                     (char*)&k_lds[BUF][0] + C);                                \
        }                                                                       \
        _Pragma("unroll")                                                       \
        for (int i = 0; i < 8; i++) {                                           \
            const int C    = i * 4096 + tid * 16;                               \
            const int drow = C >> 6;                                            \
            const int gc   = (C >> 4) & 3;                                      \
            const int gl   = gc ^ ((drow >> 1) & 3);                            \
            gl_lds16(vt_ws + vbase + (size_t)drow * 4096 + (KV0) + gl * 8,      \
                     (char*)&vt_lds[BUF][0] + C);                               \
        }                                                                       \
    } while (0)

    // prologue
    STAGE(0, kv00);
    asm volatile("s_waitcnt vmcnt(0)" ::: "memory");
    __builtin_amdgcn_s_barrier();

    int cur = 0;
    for (int it = 0; it < NK; ++it) {
        if (it + 1 < NK) STAGE(cur ^ 1, kv00 + (it + 1) * 32);

        const char* kb = (const char*)&k_lds[cur][0];
        const char* vb = (const char*)&vt_lds[cur][0];

        // ---- QK^T : S[32 rows][32 keys]; each kf read feeds 2 MFMAs
        f32x4 s00 = zf, s01 = zf, s10 = zf, s11 = zf;
        #pragma unroll
        for (int ks = 0; ks < 16; ++ks) {
            const int key0 = lane & 15;
            const s16x8 kf0 = *reinterpret_cast<const s16x8*>(
                kb + key0 * 1024 + ((ks * 64 + g * 16) ^ ((key0 & 7) << 4)));
            s00 = mfma_bf16(qf0[ks], kf0, s00);
            s10 = mfma_bf16(qf1[ks], kf0, s10);
            const int key1 = 16 + (lane & 15);
            const s16x8 kf1 = *reinterpret_cast<const s16x8*>(
                kb + key1 * 1024 + ((ks * 64 + g * 16) ^ ((key1 & 7) << 4)));
            s01 = mfma_bf16(qf0[ks], kf1, s01);
            s11 = mfma_bf16(qf1[ks], kf1, s11);
        }

        // ---- P = exp2(S - FIXED_M); accumulate l partials per-lane (no
        //      cross-lane ops in the loop); stash P to per-wave LDS bounce
        #pragma unroll
        for (int j = 0; j < 4; j++) {
            const float p00 = exp2f(s00[j] - FIXED_M);
            const float p01 = exp2f(s01[j] - FIXED_M);
            const float p10 = exp2f(s10[j] - FIXED_M);
            const float p11 = exp2f(s11[j] - FIXED_M);
            lrow[0][j] += p00 + p01;
            lrow[1][j] += p10 + p11;
            const int pr = g * 4 + j;
            p_lds[wave][pr][lane & 15]            = f2bf(p00);
            p_lds[wave][pr][16 + (lane & 15)]     = f2bf(p01);
            p_lds[wave][16 + pr][lane & 15]       = f2bf(p10);
            p_lds[wave][16 + pr][16 + (lane & 15)] = f2bf(p11);
        }

        const s16x8 pf0 = *reinterpret_cast<const s16x8*>(
            &p_lds[wave][lane & 15][g * 8]);
        const s16x8 pf1 = *reinterpret_cast<const s16x8*>(
            &p_lds[wave][16 + (lane & 15)][g * 8]);

        // ---- PV: each vf read feeds 2 MFMAs
        #pragma unroll
        for (int n = 0; n < 32; n++) {
            const int d = n * 16 + (lane & 15);
            const s16x8 vf = *reinterpret_cast<const s16x8*>(
                vb + d * 64 + ((g * 16) ^ (((d >> 1) & 3) << 4)));
            o0[n] = mfma_bf16(pf0, vf, o0[n]);
            o1[n] = mfma_bf16(pf1, vf, o1[n]);
        }

        asm volatile("s_waitcnt vmcnt(0)" ::: "memory");
        __builtin_amdgcn_s_barrier();
        cur ^= 1;
    }
#undef STAGE

    // ---- epilogue: reduce l across the 16-lane key dimension (once)
    #pragma unroll
    for (int j = 0; j < 4; j++) {
        #pragma unroll
        for (int msk = 8; msk >= 1; msk >>= 1) {
            lrow[0][j] += __shfl_xor(lrow[0][j], msk, 64);
            lrow[1][j] += __shfl_xor(lrow[1][j], msk, 64);
        }
    }

    const int qrowb = qblk * 128 + wave * 32;
    if (opart != nullptr) {
        const size_t prow8k = (size_t)batch * 4096;
        if ((lane & 15) == 0) {
            #pragma unroll
            for (int j = 0; j < 4; j++) {
                const size_t r0 = prow8k + qrowb + g * 4 + j;
                ml[((size_t)split * 8192 + r0) * 2 + 1] = lrow[0][j];
                const size_t r1 = r0 + 16;
                ml[((size_t)split * 8192 + r1) * 2 + 1] = lrow[1][j];
            }
        }
        ushort_t* op = opart + (size_t)split * 8192 * 512;
        #pragma unroll
        for (int n = 0; n < 32; n++) {
            #pragma unroll
            for (int j = 0; j < 4; j++) {
                const size_t r0 = prow8k + qrowb + g * 4 + j;
                op[r0 * 512 + n * 16 + (lane & 15)] = f2bf(o0[n][j]);
                op[(r0 + 16) * 512 + n * 16 + (lane & 15)] = f2bf(o1[n][j]);
            }
        }
    } else {
        float inv0[4], inv1[4];
        #pragma unroll
        for (int j = 0; j < 4; j++) {
            inv0[j] = 1.0f / lrow[0][j];
            inv1[j] = 1.0f / lrow[1][j];
        }
        #pragma unroll
        for (int n = 0; n < 32; n++) {
            #pragma unroll
            for (int j = 0; j < 4; j++) {
                const int row = qrowb + g * 4 + j;
                out[base + (size_t)row * 512 + n * 16 + (lane & 15)] = o0[n][j] * inv0[j];
                out[base + (size_t)(row + 16) * 512 + n * 16 + (lane & 15)] = o1[n][j] * inv1[j];
            }
        }
    }
}

// ---------------------------------------------------------------------------
// Kernel 3: merge KV-split partials. Fixed-M => all splits share the same
// offset: out = (sum_s O_s) / (sum_s l_s). 1 wave/row, 4 rows/block.
// ---------------------------------------------------------------------------
__global__ __launch_bounds__(256) void merge_kernel(
    const ushort_t* __restrict__ opart, const float* __restrict__ ml,
    float* __restrict__ out, int SP)
{
    const int row  = blockIdx.x * 4 + (threadIdx.x >> 6);
    const int lane = threadIdx.x & 63;

    float denom = 0.0f;
    for (int s = 0; s < SP; s++)
        denom += ml[((size_t)s * 8192 + row) * 2 + 1];
    const float inv = 1.0f / denom;

    float acc[8] = {};
    for (int s = 0; s < SP; s++) {
        const s16x8 v = *reinterpret_cast<const s16x8*>(
            opart + ((size_t)s * 8192 + row) * 512 + lane * 8);
        #pragma unroll
        for (int i = 0; i < 8; i++)
            acc[i] += bf2f((ushort_t)v[i]);
    }
    float* dst = out + (size_t)row * 512 + lane * 8;
    #pragma unroll
    for (int i = 0; i < 8; i++) dst[i] = acc[i] * inv;
}

extern "C" void kernel_launch(void* const* d_in, const int* in_sizes, int n_in,
                              void* d_out, int out_size, void* d_ws, size_t ws_size,
                              hipStream_t stream) {
    const float* x  = (const float*)d_in[0];
    const float* Wq = (const float*)d_in[1];
    const float* bq = (const float*)d_in[2];
    const float* Wk = (const float*)d_in[3];
    const float* bk = (const float*)d_in[4];
    const float* Wv = (const float*)d_in[5];
    const float* bv = (const float*)d_in[6];
    float* out = (float*)d_out;
    ushort_t* qkv = (ushort_t*)d_ws;  // q | k | vt, each 8192*512 bf16
    (void)in_sizes; (void)n_in; (void)out_size;

    const size_t qkv_bytes = 3ull * 8192 * 512 * 2;  // 25165824

    int SP = 0;
    if (ws_size >= qkv_bytes + 4ull * (8388608 + 65536)) SP = 4;
    else if (ws_size >= qkv_bytes + 2ull * (8388608 + 65536)) SP = 2;
    else if (ws_size >= qkv_bytes + 1ull * (8388608 + 65536)) SP = 1;

    dim3 gp(64, 4, 3);
    qkv_proj<<<gp, 256, 0, stream>>>(x, Wq, bq, Wk, bk, Wv, bv, qkv);

    if (SP > 0) {
        ushort_t* opart = qkv + 3ull * 8192 * 512;
        float* ml = (float*)(opart + (size_t)SP * 8192 * 512);
        dim3 ga(2 * SP, 32);
        attn_v5<<<ga, 256, 0, stream>>>(qkv, opart, ml, out, SP, (4096 / SP) / 32);
        merge_kernel<<<2048, 256, 0, stream>>>(opart, ml, out, SP);
    } else {
        dim3 ga(2, 32);
        attn_v5<<<ga, 256, 0, stream>>>(qkv, nullptr, nullptr, out, 1, 128);
    }
}